// Round 1
// baseline (1004.224 us; speedup 1.0000x reference)
//
#include <hip/hip_runtime.h>

#define MBn 2
#define Cn 3
#define Mn 256
#define Nn 256
#define Pn 32
#define IMG   65536      // M*N
#define CIMG  196608     // C*M*N
#define XSZ   393216     // MB*C*M*N
#define ASZ   12582912   // MB*P*C*M*N
#define EPSf  1e-8f
#define NSTEP 10

// ---------------- init: x0 = convT_fil(z, fil) ----------------
__global__ __launch_bounds__(256) void k_x0(const float* __restrict__ z, const float* __restrict__ fil,
                                            float* __restrict__ x0) {
    int idx = blockIdx.x * 256 + threadIdx.x;
    if (idx >= XSZ) return;
    int j = idx & 255, i = (idx >> 8) & 255, cm = idx >> 16;
    const float* zc = z + cm * IMG;
    float acc = 0.f;
    #pragma unroll
    for (int u = 0; u < 5; ++u) {
        int ii = i + 2 - u;
        if ((unsigned)ii >= (unsigned)Mn) continue;
        #pragma unroll
        for (int v = 0; v < 5; ++v) {
            int jj = j + 2 - v;
            if ((unsigned)jj >= (unsigned)Nn) continue;
            acc += fil[u * 5 + v] * zc[ii * Nn + jj];
        }
    }
    x0[idx] = acc;
}

// ---------------- K1: Ba partials = conv_CSC(a, B) ----------------
// grid: (mb*C)(6) x tiles(64) x pgroups(4) = 1536 blocks, 256 thr, 32x32 tile, 2x2/thread
__global__ __launch_bounds__(256) void k_convCSC(const float* __restrict__ a, const float* __restrict__ Bg,
                                                 float* __restrict__ Bap) {
    __shared__ float as_[38 * 38];
    int blk = blockIdx.x;
    int pg   = blk & 3;
    int tile = (blk >> 2) & 63;
    int cm   = blk >> 8;            // 0..5
    int c = cm % Cn, mb = cm / Cn;
    int i0 = (tile >> 3) * 32, j0 = (tile & 7) * 32;
    int tx = threadIdx.x & 15, ty = threadIdx.x >> 4;

    float acc00 = 0.f, acc01 = 0.f, acc10 = 0.f, acc11 = 0.f;
    for (int p = pg * 8; p < pg * 8 + 8; ++p) {
        const float* ap = a + ((mb * Pn + p) * Cn + c) * IMG;
        for (int l = threadIdx.x; l < 38 * 38; l += 256) {
            int r = l / 38, cc = l - r * 38;
            int gi = i0 + r - 3, gj = j0 + cc - 3;
            float vv = 0.f;
            if ((unsigned)gi < (unsigned)Mn && (unsigned)gj < (unsigned)Nn) vv = ap[gi * Nn + gj];
            as_[l] = vv;
        }
        __syncthreads();
        const float* bp = Bg + (p * Cn + c) * 49;
        #pragma unroll
        for (int u = 0; u < 8; ++u) {
            float rowv[8];
            int base = (2 * ty + u) * 38 + 2 * tx;
            #pragma unroll
            for (int k = 0; k < 8; ++k) rowv[k] = as_[base + k];
            if (u <= 6) {
                #pragma unroll
                for (int v = 0; v < 7; ++v) {
                    float bv = bp[u * 7 + v];
                    acc00 += rowv[v]     * bv;
                    acc01 += rowv[v + 1] * bv;
                }
            }
            if (u >= 1) {
                #pragma unroll
                for (int v = 0; v < 7; ++v) {
                    float bv = bp[(u - 1) * 7 + v];
                    acc10 += rowv[v]     * bv;
                    acc11 += rowv[v + 1] * bv;
                }
            }
        }
        __syncthreads();
    }
    float* out = Bap + pg * XSZ + cm * IMG;
    int oi = i0 + 2 * ty, oj = j0 + 2 * tx;
    out[oi * Nn + oj]           = acc00;
    out[oi * Nn + oj + 1]       = acc01;
    out[(oi + 1) * Nn + oj]     = acc10;
    out[(oi + 1) * Nn + oj + 1] = acc11;
}

// ---------------- K2: x update + r + v ----------------
__global__ __launch_bounds__(256) void k_xup(const float* __restrict__ xb, const float* __restrict__ Bap,
                                             const float* __restrict__ y1, const float* __restrict__ y2,
                                             const float* __restrict__ fil,
                                             const float* __restrict__ gam1, int step,
                                             float* __restrict__ xa, float* __restrict__ rr,
                                             float* __restrict__ vv) {
    int idx = blockIdx.x * 256 + threadIdx.x;
    if (idx >= XSZ) return;
    float g1 = gam1[step];
    int j = idx & 255, i = (idx >> 8) & 255, cm = idx >> 16;
    int mb = cm / Cn, c = cm - mb * Cn;
    const float* y10 = y1 + (mb * 2) * CIMG + c * IMG;
    const float* y11 = y10 + CIMG;
    int im1 = (i == 0) ? Mn - 1 : i - 1;
    int jm1 = (j == 0) ? Nn - 1 : j - 1;
    float dt = y10[im1 * Nn + j] - y10[i * Nn + j] + y11[i * Nn + jm1] - y11[i * Nn + j];
    const float* y2c = y2 + cm * IMG;
    float cf = 0.f;
    #pragma unroll
    for (int u = 0; u < 5; ++u) {
        int ii = i + 2 - u;
        if ((unsigned)ii >= (unsigned)Mn) continue;
        #pragma unroll
        for (int v = 0; v < 5; ++v) {
            int jj = j + 2 - v;
            if ((unsigned)jj >= (unsigned)Nn) continue;
            cf += fil[u * 5 + v] * y2c[ii * Nn + jj];
        }
    }
    float bav = Bap[idx] + Bap[XSZ + idx] + Bap[2 * XSZ + idx] + Bap[3 * XSZ + idx];
    float xv = xb[idx];
    float xn = xv - g1 * (xv - bav + dt + cf);
    xn = fminf(fmaxf(xn, 0.f), 1.f);
    xa[idx] = xn;
    rr[idx] = xv - bav;
    vv[idx] = 2.f * xn - xv;
}

// ---------------- K3: a update (in place): a = soft(a + g2*convT_CSC(r,B), g2*l1) ----------------
// grid: cm(6) x tiles(64) x p(32) = 12288 blocks
__global__ __launch_bounds__(256) void k_aup(float* __restrict__ a, const float* __restrict__ rr,
                                             const float* __restrict__ Bg,
                                             const float* __restrict__ lam1, const float* __restrict__ gam2,
                                             int step) {
    __shared__ float rs[38 * 38];
    int blk = blockIdx.x;
    int p    = blk & 31;
    int tile = (blk >> 5) & 63;
    int cm   = blk >> 11;
    int c = cm % Cn, mb = cm / Cn;
    int i0 = (tile >> 3) * 32, j0 = (tile & 7) * 32;
    int tx = threadIdx.x & 15, ty = threadIdx.x >> 4;

    const float* rp = rr + cm * IMG;
    for (int l = threadIdx.x; l < 38 * 38; l += 256) {
        int r = l / 38, cc = l - r * 38;
        int gi = i0 + r - 3, gj = j0 + cc - 3;
        float vv = 0.f;
        if ((unsigned)gi < (unsigned)Mn && (unsigned)gj < (unsigned)Nn) vv = rp[gi * Nn + gj];
        rs[l] = vv;
    }
    __syncthreads();
    const float* bp = Bg + (p * Cn + c) * 49;
    float acc00 = 0.f, acc01 = 0.f, acc10 = 0.f, acc11 = 0.f;
    #pragma unroll
    for (int u = 0; u < 8; ++u) {
        float rowv[8];
        int base = (2 * ty + u) * 38 + 2 * tx;
        #pragma unroll
        for (int k = 0; k < 8; ++k) rowv[k] = rs[base + k];
        if (u <= 6) {
            #pragma unroll
            for (int v = 0; v < 7; ++v) {
                float bv = bp[(6 - u) * 7 + (6 - v)];          // flipped: true convolution
                acc00 += rowv[v]     * bv;
                acc01 += rowv[v + 1] * bv;
            }
        }
        if (u >= 1) {
            #pragma unroll
            for (int v = 0; v < 7; ++v) {
                float bv = bp[(6 - (u - 1)) * 7 + (6 - v)];
                acc10 += rowv[v]     * bv;
                acc11 += rowv[v + 1] * bv;
            }
        }
    }
    float g2 = gam2[step], l1v = lam1[step];
    float thr = g2 * l1v;
    float* apo = a + ((mb * Pn + p) * Cn + c) * IMG;
    int oi = i0 + 2 * ty, oj = j0 + 2 * tx;
    {
        int id = oi * Nn + oj;           float av = apo[id] + g2 * acc00;
        apo[id] = copysignf(fmaxf(fabsf(av) - thr, 0.f), av);
    }
    {
        int id = oi * Nn + oj + 1;       float av = apo[id] + g2 * acc01;
        apo[id] = copysignf(fmaxf(fabsf(av) - thr, 0.f), av);
    }
    {
        int id = (oi + 1) * Nn + oj;     float av = apo[id] + g2 * acc10;
        apo[id] = copysignf(fmaxf(fabsf(av) - thr, 0.f), av);
    }
    {
        int id = (oi + 1) * Nn + oj + 1; float av = apo[id] + g2 * acc11;
        apo[id] = copysignf(fmaxf(fabsf(av) - thr, 0.f), av);
    }
}

// ---------------- K4: y1 update (in place) ----------------
__global__ __launch_bounds__(256) void k_y1up(float* __restrict__ y1, const float* __restrict__ vv,
                                              const float* __restrict__ lam2, const float* __restrict__ gam3,
                                              int step) {
    int idx = blockIdx.x * 256 + threadIdx.x;
    if (idx >= XSZ) return;
    float g3 = gam3[step], l2v = lam2[step];
    int j = idx & 255, i = (idx >> 8) & 255, cm = idx >> 16;
    int mb = cm / Cn, c = cm - mb * Cn;
    const float* vc = vv + cm * IMG;
    int ip1 = (i == Mn - 1) ? 0 : i + 1;
    int jp1 = (j == Nn - 1) ? 0 : j + 1;
    float vij = vc[i * Nn + j];
    float d0 = vc[ip1 * Nn + j] - vij;
    float d1 = vc[i * Nn + jp1] - vij;
    float* y10 = y1 + (mb * 2) * CIMG + c * IMG + i * Nn + j;
    float* y11 = y10 + CIMG;
    float t0 = *y10 + g3 * d0;
    float t1 = *y11 + g3 * d1;
    float inv = 1.f / (g3 + EPSf);
    float w0 = t0 * inv, w1 = t1 * inv;
    float nrm = sqrtf(w0 * w0 + w1 * w1);
    float fac = fmaxf(1.f - (l2v * inv) / fmaxf(nrm, EPSf), 0.f);
    *y10 = t0 - g3 * (w0 * fac);
    *y11 = t1 - g3 * (w1 * fac);
}

// ---------------- K5a: y2 += g3*conv_fil(v); partial sums of ||y2/(g3+eps)-z||^2 ----------------
__global__ __launch_bounds__(256) void k_y2a(float* __restrict__ y2, const float* __restrict__ vv,
                                             const float* __restrict__ fil, const float* __restrict__ z,
                                             const float* __restrict__ gam3, int step,
                                             float* __restrict__ partial) {
    __shared__ float red[256];
    int tid = threadIdx.x;
    int idx = blockIdx.x * 256 + tid;
    float g3 = gam3[step];
    int j = idx & 255, i = (idx >> 8) & 255, cm = idx >> 16;
    const float* vc = vv + cm * IMG;
    float cf = 0.f;
    #pragma unroll
    for (int u = 0; u < 5; ++u) {
        int ii = i + u - 2;
        if ((unsigned)ii >= (unsigned)Mn) continue;
        #pragma unroll
        for (int v = 0; v < 5; ++v) {
            int jj = j + v - 2;
            if ((unsigned)jj >= (unsigned)Nn) continue;
            cf += fil[u * 5 + v] * vc[ii * Nn + jj];
        }
    }
    float t = y2[idx] + g3 * cf;
    y2[idx] = t;
    float d = t / (g3 + EPSf) - z[idx];
    red[tid] = d * d;
    __syncthreads();
    #pragma unroll
    for (int s = 128; s > 0; s >>= 1) {
        if (tid < s) red[tid] += red[tid + s];
        __syncthreads();
    }
    if (tid == 0) partial[blockIdx.x] = red[0];
}

// ---------------- K5n: deterministic norm reduce (2 blocks, one per mb) ----------------
__global__ __launch_bounds__(256) void k_norm(const float* __restrict__ partial, float* __restrict__ norm2) {
    __shared__ float red[256];
    int tid = threadIdx.x;
    float s = 0.f;
    for (int l = tid; l < 768; l += 256) s += partial[blockIdx.x * 768 + l];
    red[tid] = s;
    __syncthreads();
    #pragma unroll
    for (int k = 128; k > 0; k >>= 1) {
        if (tid < k) red[tid] += red[tid + k];
        __syncthreads();
    }
    if (tid == 0) norm2[blockIdx.x] = sqrtf(red[0]);
}

// ---------------- K5b: y2 finalize ----------------
__global__ __launch_bounds__(256) void k_y2b(float* __restrict__ y2, const float* __restrict__ z,
                                             const float* __restrict__ gam3, int step,
                                             const float* __restrict__ norm2) {
    int idx = blockIdx.x * 256 + threadIdx.x;
    if (idx >= XSZ) return;
    float g3 = gam3[step];
    float inv = 1.f / (g3 + EPSf);
    int mb = (idx >= CIMG) ? 1 : 0;
    float radius = 0.05f * sqrtf((float)CIMG);
    float t = y2[idx], zv = z[idx];
    float w = t * inv;
    float nrm = norm2[mb];
    float scale = fminf(1.f, radius / fmaxf(nrm, EPSf));
    float pj = zv + (w - zv) * scale;
    y2[idx] = t - g3 * pj;
}

extern "C" void kernel_launch(void* const* d_in, const int* in_sizes, int n_in,
                              void* d_out, int out_size, void* d_ws, size_t ws_size,
                              hipStream_t stream) {
    const float* z      = (const float*)d_in[0];
    const float* a_init = (const float*)d_in[1];
    const float* B      = (const float*)d_in[2];
    const float* fil    = (const float*)d_in[3];
    const float* lam1   = (const float*)d_in[4];
    const float* lam2   = (const float*)d_in[5];
    const float* gam1   = (const float*)d_in[6];
    const float* gam2   = (const float*)d_in[7];
    const float* gam3   = (const float*)d_in[8];

    float* ws = (float*)d_ws;
    float* a     = ws;                    // ASZ
    float* xA    = a + ASZ;               // XSZ
    float* xB    = xA + XSZ;              // XSZ
    float* Bap   = xB + XSZ;              // 4*XSZ
    float* rr    = Bap + 4 * XSZ;         // XSZ
    float* vv    = rr + XSZ;              // XSZ
    float* y1    = vv + XSZ;              // 2*XSZ
    float* y2    = y1 + 2 * XSZ;          // XSZ
    float* part  = y2 + XSZ;              // 1536
    float* norm2 = part + 1536;           // 2

    // init
    hipMemcpyAsync(a, a_init, (size_t)ASZ * sizeof(float), hipMemcpyDeviceToDevice, stream);
    hipMemsetAsync(y1, 0, (size_t)2 * XSZ * sizeof(float), stream);
    hipMemsetAsync(y2, 0, (size_t)XSZ * sizeof(float), stream);
    k_x0<<<XSZ / 256, 256, 0, stream>>>(z, fil, xA);

    float* xin = xA;
    float* xout = xB;
    for (int s = 0; s < NSTEP; ++s) {
        k_convCSC<<<1536, 256, 0, stream>>>(a, B, Bap);
        k_xup<<<XSZ / 256, 256, 0, stream>>>(xin, Bap, y1, y2, fil, gam1, s, xout, rr, vv);
        k_aup<<<12288, 256, 0, stream>>>(a, rr, B, lam1, gam2, s);
        k_y1up<<<XSZ / 256, 256, 0, stream>>>(y1, vv, lam2, gam3, s);
        k_y2a<<<XSZ / 256, 256, 0, stream>>>(y2, vv, fil, z, gam3, s, part);
        k_norm<<<2, 256, 0, stream>>>(part, norm2);
        k_y2b<<<XSZ / 256, 256, 0, stream>>>(y2, z, gam3, s, norm2);
        float* t = xin; xin = xout; xout = t;
    }

    hipMemcpyAsync(d_out, xin, (size_t)XSZ * sizeof(float), hipMemcpyDeviceToDevice, stream);
}